// Round 12
// baseline (211.219 us; speedup 1.0000x reference)
//
#include <hip/hip_runtime.h>
#include <hip/hip_cooperative_groups.h>
#include <cfloat>
#include <cstddef>

namespace cg = cooperative_groups;

#define NBATCH 2
#define NPTS   5000
#define NF     64
#define NB     10      // bins = N / BIN_SIZE
#define BINSZ  500
#define TOPK   5
#define ROTCOLS 100    // MAX_NUM_BINS/2 columns in rotations

#define NCB    8                       // col-blocks per group
#define CBS    64                      // cols per col-block (last = 52)
#define NCAND  (NCB * TOPK)            // 40 candidates per row
#define OUT4   (NBATCH * NPTS * NPTS / 4)   // 12.5M float4 in d_out
#define GRID   256                     // 1 block/CU, guaranteed co-resident

union SMem {                           // 30.9 KB max (sort phase)
    float srot[NF * 5];
    struct { int bin[NPTS]; int hist[256][NB]; int part[NB][16]; int tot[NB + 1]; } so;
    struct { float cols[CBS * NF]; float cna[CBS]; } pa;
};

// ---------------------------------------------------------------------------
// Single cooperative kernel: P0 bin/norm + zero -> P1 sort -> P2 pair/top5
// -> P3 merge/inject. All phase bodies are the bit-validated R5/R10 versions.
// ---------------------------------------------------------------------------
__global__ __launch_bounds__(256, 2) void fused_k(const float* __restrict__ pts,
                                                  const float* __restrict__ rot,
                                                  float* __restrict__ na,
                                                  int* __restrict__ bin_idx,
                                                  int* __restrict__ order,
                                                  float* __restrict__ wv,
                                                  int* __restrict__ wd,
                                                  float* __restrict__ out) {
    cg::grid_group gg = cg::this_grid();
    __shared__ SMem sm;
    const int bx = blockIdx.x;
    const int t  = threadIdx.x;

    // ---------------- P0a: bin + norm (validated wave-per-point body) -------
    for (int i = t; i < NF * 5; i += 256) {          // full 320-element fill
        int f = i / 5, h = i - 5 * f;
        sm.srot[i] = rot[f * ROTCOLS + h];
    }
    __syncthreads();
    for (int rnd = 0; rnd < 10; ++rnd) {             // 40 points per block
        int pt = bx * 40 + rnd * 4 + (t >> 6);
        if (pt < NBATCH * NPTS) {
            int lane = t & 63;
            float p  = pts[(size_t)pt * NF + lane];
            float nn = p * p;
            float c0 = p * sm.srot[lane * 5 + 0];
            float c1 = p * sm.srot[lane * 5 + 1];
            float c2 = p * sm.srot[lane * 5 + 2];
            float c3 = p * sm.srot[lane * 5 + 3];
            float c4 = p * sm.srot[lane * 5 + 4];
            #pragma unroll
            for (int off = 32; off > 0; off >>= 1) {
                nn += __shfl_xor(nn, off);
                c0 += __shfl_xor(c0, off);
                c1 += __shfl_xor(c1, off);
                c2 += __shfl_xor(c2, off);
                c3 += __shfl_xor(c3, off);
                c4 += __shfl_xor(c4, off);
            }
            if (lane == 0) {
                float c[5] = {c0, c1, c2, c3, c4};
                float bv = c[0]; int bi = 0;
                #pragma unroll
                for (int h = 1; h < 5; ++h) if (c[h] > bv) { bv = c[h]; bi = h; }
                #pragma unroll
                for (int h = 0; h < 5; ++h) if (-c[h] > bv) { bv = -c[h]; bi = h + 5; }
                bin_idx[pt] = bi;                    // first-max wins (argmax)
                na[pt] = nn;
            }
        }
    }

    // ---------------- P0b: zero own slice of d_out (coalesced float4) ------
    {
        const int chunk = (OUT4 + GRID - 1) / GRID;  // 48829
        size_t lo = (size_t)bx * chunk;
        size_t hi = lo + chunk; if (hi > (size_t)OUT4) hi = OUT4;
        float4* o4 = (float4*)out;
        const float4 z4 = make_float4(0.f, 0.f, 0.f, 0.f);
        for (size_t i = lo + t; i < hi; i += 256) o4[i] = z4;
    }
    gg.sync();

    // ---------------- P1: stable counting sort (validated, blocks 0,1) -----
    if (bx < NBATCH) {
        const int b = bx;
        const int w = t >> 6, lane = t & 63;
        for (int i = t; i < NPTS; i += 256) sm.so.bin[i] = bin_idx[b * NPTS + i];
        #pragma unroll
        for (int h = 0; h < NB; ++h) sm.so.hist[t][h] = 0;
        __syncthreads();

        const int CH = (NPTS + 255) / 256;           // 20
        const int i0 = t * CH;
        const int i1 = (i0 + CH < NPTS) ? (i0 + CH) : NPTS;
        for (int i = i0; i < i1; ++i) sm.so.hist[t][sm.so.bin[i]]++;
        __syncthreads();

        if (t < NB * 16) {
            int h = t >> 4, s = t & 15;
            int sum = 0;
            #pragma unroll
            for (int k = 0; k < 16; ++k) sum += sm.so.hist[s * 16 + k][h];
            sm.so.part[h][s] = sum;
        }
        __syncthreads();
        if (t < NB) {
            int tot = 0;
            #pragma unroll
            for (int s = 0; s < 16; ++s) tot += sm.so.part[t][s];
            sm.so.tot[t + 1] = tot;
        }
        __syncthreads();
        if (t == 0) {
            sm.so.tot[0] = 0;
            for (int h = 1; h <= NB; ++h) sm.so.tot[h] += sm.so.tot[h - 1];
        }
        __syncthreads();

        for (int h = w; h < NB; h += 4) {
            int base = lane * 4;
            int v0 = sm.so.hist[base + 0][h];
            int v1 = sm.so.hist[base + 1][h];
            int v2 = sm.so.hist[base + 2][h];
            int v3 = sm.so.hist[base + 3][h];
            int lt = v0 + v1 + v2 + v3;
            int x = lt;
            #pragma unroll
            for (int off = 1; off < 64; off <<= 1) {
                int y = __shfl_up(x, off);
                if (lane >= off) x += y;
            }
            int excl = x - lt + sm.so.tot[h];
            sm.so.hist[base + 0][h] = excl;
            sm.so.hist[base + 1][h] = excl + v0;
            sm.so.hist[base + 2][h] = excl + v0 + v1;
            sm.so.hist[base + 3][h] = excl + v0 + v1 + v2;
        }
        __syncthreads();

        for (int i = i0; i < i1; ++i) {
            int h = sm.so.bin[i];
            order[b * NPTS + sm.so.hist[t][h]++] = i;
        }
    }
    gg.sync();

    // ---------------- P2: pairwise d^2 + per-colblock top-5 (validated R5) -
    if (bx < NBATCH * NB * NCB) {
        const int g   = bx / NCB;
        const int cb  = bx - g * NCB;
        const int b   = g / NB;
        const int grp = g - b * NB;
        const int c0  = cb * CBS;
        const int ncols = (c0 + CBS <= BINSZ) ? CBS : (BINSZ - c0);   // 64 or 52

        const int* ord = order + b * NPTS + grp * BINSZ;
        const float4* p4 = (const float4*)(pts + (size_t)b * NPTS * NF);
        float4* sc4 = (float4*)sm.pa.cols;

        for (int i = t; i < ncols * 16; i += 256) {
            int c = i >> 4, q = i & 15;
            sc4[c * 16 + q] = p4[(size_t)ord[c0 + c] * 16 + q];
        }
        if (t < ncols) sm.pa.cna[t] = na[b * NPTS + ord[c0 + t]];
        __syncthreads();

        const int p0 = t, p1 = t + 256;
        const bool h1 = (p1 < BINSZ);
        const int gi0 = ord[p0];
        const int gi1 = h1 ? ord[p1] : gi0;
        float4 r0[16], r1[16];
        #pragma unroll
        for (int q = 0; q < 16; ++q) {
            r0[q] = p4[(size_t)gi0 * 16 + q];
            r1[q] = p4[(size_t)gi1 * 16 + q];
        }
        const float na0 = na[b * NPTS + gi0];
        const float na1 = na[b * NPTS + gi1];

        float tv0[TOPK], tv1[TOPK]; int tp0[TOPK], tp1[TOPK];
        #pragma unroll
        for (int s = 0; s < TOPK; ++s) { tv0[s] = FLT_MAX; tv1[s] = FLT_MAX; tp0[s] = 0; tp1[s] = 0; }

        for (int c = 0; c < ncols; ++c) {
            const float4* cq = sc4 + c * 16;     // wave-uniform broadcast reads
            float a0 = 0.f, a1 = 0.f;
            #pragma unroll
            for (int q = 0; q < 16; ++q) {       // identical accumulation order
                float4 cc = cq[q];
                a0 += r0[q].x * cc.x; a0 += r0[q].y * cc.y;
                a0 += r0[q].z * cc.z; a0 += r0[q].w * cc.w;
                a1 += r1[q].x * cc.x; a1 += r1[q].y * cc.y;
                a1 += r1[q].z * cc.z; a1 += r1[q].w * cc.w;
            }
            const float cna = sm.pa.cna[c];
            const int pos = c0 + c;
            float d0 = na0 - 2.f * a0 + cna;
            float d1 = na1 - 2.f * a1 + cna;
            if (d0 < tv0[TOPK - 1]) {            // strict <: ties keep earlier pos
                tv0[TOPK - 1] = d0; tp0[TOPK - 1] = pos;
                #pragma unroll
                for (int s = TOPK - 1; s > 0; --s) {
                    if (tv0[s] < tv0[s - 1]) {
                        float fv = tv0[s]; tv0[s] = tv0[s - 1]; tv0[s - 1] = fv;
                        int   fi = tp0[s]; tp0[s] = tp0[s - 1]; tp0[s - 1] = fi;
                    }
                }
            }
            if (h1 && d1 < tv1[TOPK - 1]) {
                tv1[TOPK - 1] = d1; tp1[TOPK - 1] = pos;
                #pragma unroll
                for (int s = TOPK - 1; s > 0; --s) {
                    if (tv1[s] < tv1[s - 1]) {
                        float fv = tv1[s]; tv1[s] = tv1[s - 1]; tv1[s - 1] = fv;
                        int   fi = tp1[s]; tp1[s] = tp1[s - 1]; tp1[s - 1] = fi;
                    }
                }
            }
        }

        const int slotbase = (b * NB + grp) * BINSZ;
        {
            size_t wbase = ((size_t)(slotbase + p0) * NCB + cb) * TOPK;
            #pragma unroll
            for (int s = 0; s < TOPK; ++s) { wv[wbase + s] = tv0[s]; wd[wbase + s] = tp0[s]; }
        }
        if (h1) {
            size_t wbase = ((size_t)(slotbase + p1) * NCB + cb) * TOPK;
            #pragma unroll
            for (int s = 0; s < TOPK; ++s) { wv[wbase + s] = tv1[s]; wd[wbase + s] = tp1[s]; }
        }
    }
    gg.sync();

    // ---------------- P3: merge 8x top-5 by (d2,pos) + inject (validated) --
    {
        const int slot = bx * 256 + t;
        if (slot < NBATCH * NPTS) {
            const int b   = slot / (NB * BINSZ);
            const int rem = slot - b * NB * BINSZ;
            const int grp = rem / BINSZ;
            const int p   = rem - grp * BINSZ;
            const int* ord = order + b * NPTS + grp * BINSZ;
            const int src = ord[p];

            float cv[NCAND]; int cp[NCAND];
            const size_t base = (size_t)slot * NCAND;
            #pragma unroll
            for (int k = 0; k < NCAND; ++k) { cv[k] = wv[base + k]; cp[k] = wd[base + k]; }

            unsigned long long used = 0;
            float* orow = out + ((size_t)b * NPTS + src) * NPTS;
            #pragma unroll
            for (int s = 0; s < TOPK; ++s) {
                float bv = FLT_MAX; int bp = 0x7fffffff; int bk = 0;
                #pragma unroll
                for (int k = 0; k < NCAND; ++k) {
                    bool ok = !((used >> k) & 1ull);
                    bool better = ok && ((cv[k] < bv) || (cv[k] == bv && cp[k] < bp));
                    if (better) { bv = cv[k]; bp = cp[k]; bk = k; }
                }
                used |= (1ull << bk);
                float val = expf(-0.1f * sqrtf(fmaxf(bv, 1e-6f)));
                orow[ord[bp]] = val;
            }
        }
    }
}

// ---------------------------------------------------------------------------
// Fallback kernels (R5-validated chain) in case cooperative launch fails.
// ---------------------------------------------------------------------------
__global__ __launch_bounds__(256) void fb_zero_k(float* __restrict__ out) {
    const int chunk = (OUT4 + 2047) / 2048;
    size_t lo = (size_t)blockIdx.x * chunk;
    size_t hi = lo + chunk; if (hi > (size_t)OUT4) hi = OUT4;
    float4* o4 = (float4*)out;
    const float4 z4 = make_float4(0.f, 0.f, 0.f, 0.f);
    for (size_t i = lo + threadIdx.x; i < hi; i += 256) o4[i] = z4;
}
__global__ __launch_bounds__(256) void fb_all_k(const float* __restrict__ pts,
                                                const float* __restrict__ rot,
                                                float* __restrict__ na,
                                                int* __restrict__ bin_idx,
                                                int* __restrict__ order,
                                                float* __restrict__ wv,
                                                int* __restrict__ wd,
                                                float* __restrict__ out,
                                                const int* __restrict__ phase) {
    // unused in normal operation; kept minimal (fallback path relaunches fused_k
    // phases would be complex — fallback simply not expected to trigger).
}

// ---------------------------------------------------------------------------
extern "C" void kernel_launch(void* const* d_in, const int* in_sizes, int n_in,
                              void* d_out, int out_size, void* d_ws, size_t ws_size,
                              hipStream_t stream) {
    const float* points = (const float*)d_in[0];
    const float* rot    = (const float*)d_in[1];
    float* out = (float*)d_out;

    char* ws = (char*)d_ws;
    float* na      = (float*)ws; ws += NBATCH * NPTS * sizeof(float);
    int*   bin_idx = (int*)ws;   ws += NBATCH * NPTS * sizeof(int);
    int*   order   = (int*)ws;   ws += NBATCH * NPTS * sizeof(int);
    float* wv      = (float*)ws; ws += (size_t)NBATCH * NPTS * NCAND * sizeof(float);
    int*   wd      = (int*)ws;   // total ws use ~3.4 MB

    void* args[] = {(void*)&points, (void*)&rot, (void*)&na, (void*)&bin_idx,
                    (void*)&order, (void*)&wv, (void*)&wd, (void*)&out};
    hipLaunchCooperativeKernel((const void*)fused_k, dim3(GRID), dim3(256),
                               args, 0, stream);
}

// Round 13
// 110.048 us; speedup vs baseline: 1.9193x; 1.9193x over previous
//
#include <hip/hip_runtime.h>
#include <cfloat>
#include <cstddef>

#define NBATCH 2
#define NPTS   5000
#define NF     64
#define NB     10      // bins = N / BIN_SIZE
#define BINSZ  500
#define TOPK   5
#define ROTCOLS 100    // MAX_NUM_BINS/2 columns in rotations

#define NCB    8                       // col-blocks per group
#define CBS    64                      // cols per col-block (last = 52)
#define NCAND  (NCB * TOPK)            // 40 candidates per row

// ---------------------------------------------------------------------------
// A: per-point LSH bin + squared norm. One wave per point, 4 waves/blk.
// (R5-validated verbatim.)
// ---------------------------------------------------------------------------
__global__ __launch_bounds__(256) void bin_norm_k(const float* __restrict__ pts,
                                                  const float* __restrict__ rot,
                                                  int* __restrict__ bin_idx,
                                                  float* __restrict__ na) {
    __shared__ float srot[NF * 5];
    const int t = threadIdx.x;
    for (int i = t; i < NF * 5; i += 256) {      // full 320-element fill
        int f = i / 5, h = i - 5 * f;
        srot[i] = rot[f * ROTCOLS + h];
    }
    __syncthreads();

    int pt   = blockIdx.x * 4 + (t >> 6);
    int lane = t & 63;
    float p  = pts[(size_t)pt * NF + lane];
    float nn = p * p;
    float c0 = p * srot[lane * 5 + 0];
    float c1 = p * srot[lane * 5 + 1];
    float c2 = p * srot[lane * 5 + 2];
    float c3 = p * srot[lane * 5 + 3];
    float c4 = p * srot[lane * 5 + 4];
    #pragma unroll
    for (int off = 32; off > 0; off >>= 1) {
        nn += __shfl_xor(nn, off);
        c0 += __shfl_xor(c0, off);
        c1 += __shfl_xor(c1, off);
        c2 += __shfl_xor(c2, off);
        c3 += __shfl_xor(c3, off);
        c4 += __shfl_xor(c4, off);
    }
    if (lane == 0) {
        float c[5] = {c0, c1, c2, c3, c4};
        float bv = c[0]; int bi = 0;
        #pragma unroll
        for (int h = 1; h < 5; ++h) if (c[h] > bv) { bv = c[h]; bi = h; }
        #pragma unroll
        for (int h = 0; h < 5; ++h) if (-c[h] > bv) { bv = -c[h]; bi = h + 5; }
        bin_idx[pt] = bi;   // first-max wins, matches jnp.argmax
        na[pt] = nn;
    }
}

// ---------------------------------------------------------------------------
// B: stable counting sort, fully parallelized phases. (R5-validated verbatim.)
// ---------------------------------------------------------------------------
__global__ __launch_bounds__(256) void sort_k(const int* __restrict__ bin_idx,
                                              int* __restrict__ order) {
    const int b = blockIdx.x;
    const int t = threadIdx.x;
    const int w = t >> 6, lane = t & 63;
    __shared__ int sh_bin[NPTS];
    __shared__ int sh_hist[256][NB];
    __shared__ int sh_part[NB][16];
    __shared__ int sh_tot[NB + 1];

    for (int i = t; i < NPTS; i += 256) sh_bin[i] = bin_idx[b * NPTS + i];
    #pragma unroll
    for (int h = 0; h < NB; ++h) sh_hist[t][h] = 0;
    __syncthreads();

    const int CH = (NPTS + 255) / 256;            // 20
    const int i0 = t * CH;
    const int i1 = (i0 + CH < NPTS) ? (i0 + CH) : NPTS;
    for (int i = i0; i < i1; ++i) sh_hist[t][sh_bin[i]]++;
    __syncthreads();

    if (t < NB * 16) {
        int h = t >> 4, s = t & 15;
        int sum = 0;
        #pragma unroll
        for (int k = 0; k < 16; ++k) sum += sh_hist[s * 16 + k][h];
        sh_part[h][s] = sum;
    }
    __syncthreads();
    if (t < NB) {
        int tot = 0;
        #pragma unroll
        for (int s = 0; s < 16; ++s) tot += sh_part[t][s];
        sh_tot[t + 1] = tot;
    }
    __syncthreads();
    if (t == 0) {
        sh_tot[0] = 0;
        for (int h = 1; h <= NB; ++h) sh_tot[h] += sh_tot[h - 1];
    }
    __syncthreads();

    for (int h = w; h < NB; h += 4) {
        int base = lane * 4;
        int v0 = sh_hist[base + 0][h];
        int v1 = sh_hist[base + 1][h];
        int v2 = sh_hist[base + 2][h];
        int v3 = sh_hist[base + 3][h];
        int lt = v0 + v1 + v2 + v3;
        int x = lt;
        #pragma unroll
        for (int off = 1; off < 64; off <<= 1) {
            int y = __shfl_up(x, off);
            if (lane >= off) x += y;
        }
        int excl = x - lt + sh_tot[h];
        sh_hist[base + 0][h] = excl;
        sh_hist[base + 1][h] = excl + v0;
        sh_hist[base + 2][h] = excl + v0 + v1;
        sh_hist[base + 3][h] = excl + v0 + v1 + v2;
    }
    __syncthreads();

    for (int i = i0; i < i1; ++i) {
        int h = sh_bin[i];
        order[b * NPTS + sh_hist[t][h]++] = i;
    }
}

// ---------------------------------------------------------------------------
// C: per-group pairwise d^2 + per-colblock top-5 -> compact candidates.
// Grid: 20 groups x 8 col-blocks = 160 blocks of 256 threads. (R5-validated
// compute body verbatim; zero-ballast branch removed.)
// ---------------------------------------------------------------------------
__global__ __launch_bounds__(256) void pair_topk_k(const float* __restrict__ pts,
                                                   const float* __restrict__ na,
                                                   const int* __restrict__ order,
                                                   float* __restrict__ wv,
                                                   int* __restrict__ wd) {
    const int bx  = blockIdx.x;
    const int tid = threadIdx.x;
    const int g   = bx / NCB;
    const int cb  = bx - g * NCB;
    const int b   = g / NB;
    const int grp = g - b * NB;
    const int c0  = cb * CBS;
    const int ncols = (c0 + CBS <= BINSZ) ? CBS : (BINSZ - c0);   // 64 or 52

    __shared__ float sh_cols[CBS * NF];      // 16 KB
    __shared__ float sh_cna[CBS];

    const int* ord = order + b * NPTS + grp * BINSZ;
    const float4* p4 = (const float4*)(pts + (size_t)b * NPTS * NF);
    float4* sc4 = (float4*)sh_cols;

    for (int i = tid; i < ncols * 16; i += 256) {
        int c = i >> 4, q = i & 15;
        sc4[c * 16 + q] = p4[(size_t)ord[c0 + c] * 16 + q];
    }
    if (tid < ncols) sh_cna[tid] = na[b * NPTS + ord[c0 + tid]];
    __syncthreads();

    const int p0 = tid, p1 = tid + 256;
    const bool h1 = (p1 < BINSZ);            // threads 0..243 own a 2nd row
    const int gi0 = ord[p0];
    const int gi1 = h1 ? ord[p1] : gi0;
    float4 r0[16], r1[16];
    #pragma unroll
    for (int q = 0; q < 16; ++q) {
        r0[q] = p4[(size_t)gi0 * 16 + q];
        r1[q] = p4[(size_t)gi1 * 16 + q];
    }
    const float na0 = na[b * NPTS + gi0];
    const float na1 = na[b * NPTS + gi1];

    float tv0[TOPK], tv1[TOPK]; int tp0[TOPK], tp1[TOPK];
    #pragma unroll
    for (int s = 0; s < TOPK; ++s) { tv0[s] = FLT_MAX; tv1[s] = FLT_MAX; tp0[s] = 0; tp1[s] = 0; }

    for (int c = 0; c < ncols; ++c) {
        const float4* cq = sc4 + c * 16;     // wave-uniform broadcast reads
        float a0 = 0.f, a1 = 0.f;
        #pragma unroll
        for (int q = 0; q < 16; ++q) {       // identical accumulation order everywhere
            float4 cc = cq[q];
            a0 += r0[q].x * cc.x; a0 += r0[q].y * cc.y;
            a0 += r0[q].z * cc.z; a0 += r0[q].w * cc.w;
            a1 += r1[q].x * cc.x; a1 += r1[q].y * cc.y;
            a1 += r1[q].z * cc.z; a1 += r1[q].w * cc.w;
        }
        const float cna = sh_cna[c];
        const int pos = c0 + c;
        float d0 = na0 - 2.f * a0 + cna;
        float d1 = na1 - 2.f * a1 + cna;
        if (d0 < tv0[TOPK - 1]) {            // strict <: ties keep earlier pos
            tv0[TOPK - 1] = d0; tp0[TOPK - 1] = pos;
            #pragma unroll
            for (int s = TOPK - 1; s > 0; --s) {
                if (tv0[s] < tv0[s - 1]) {
                    float fv = tv0[s]; tv0[s] = tv0[s - 1]; tv0[s - 1] = fv;
                    int   fi = tp0[s]; tp0[s] = tp0[s - 1]; tp0[s - 1] = fi;
                }
            }
        }
        if (h1 && d1 < tv1[TOPK - 1]) {
            tv1[TOPK - 1] = d1; tp1[TOPK - 1] = pos;
            #pragma unroll
            for (int s = TOPK - 1; s > 0; --s) {
                if (tv1[s] < tv1[s - 1]) {
                    float fv = tv1[s]; tv1[s] = tv1[s - 1]; tv1[s - 1] = fv;
                    int   fi = tp1[s]; tp1[s] = tp1[s - 1]; tp1[s - 1] = fi;
                }
            }
        }
    }

    const int slotbase = (b * NB + grp) * BINSZ;
    {
        size_t wbase = ((size_t)(slotbase + p0) * NCB + cb) * TOPK;
        #pragma unroll
        for (int s = 0; s < TOPK; ++s) { wv[wbase + s] = tv0[s]; wd[wbase + s] = tp0[s]; }
    }
    if (h1) {
        size_t wbase = ((size_t)(slotbase + p1) * NCB + cb) * TOPK;
        #pragma unroll
        for (int s = 0; s < TOPK; ++s) { wv[wbase + s] = tv1[s]; wd[wbase + s] = tp1[s]; }
    }
}

// ---------------------------------------------------------------------------
// M: per-row merge of 8 partial top-5 lists by exact (d2, pos) lexicographic
// order (== single-scan selection), then exp + inject into the memset-zeroed
// d_out. (R5-validated verbatim.)
// ---------------------------------------------------------------------------
__global__ __launch_bounds__(256) void merge_inject_k(const float* __restrict__ wv,
                                                      const int* __restrict__ wd,
                                                      const int* __restrict__ order,
                                                      float* __restrict__ out) {
    const int slot = blockIdx.x * 256 + threadIdx.x;
    if (slot >= NBATCH * NPTS) return;
    const int b   = slot / (NB * BINSZ);
    const int rem = slot - b * NB * BINSZ;
    const int grp = rem / BINSZ;
    const int p   = rem - grp * BINSZ;
    const int* ord = order + b * NPTS + grp * BINSZ;
    const int src = ord[p];

    float cv[NCAND]; int cp[NCAND];
    const size_t base = (size_t)slot * NCAND;
    #pragma unroll
    for (int k = 0; k < NCAND; ++k) { cv[k] = wv[base + k]; cp[k] = wd[base + k]; }

    unsigned long long used = 0;
    float* orow = out + ((size_t)b * NPTS + src) * NPTS;
    #pragma unroll
    for (int s = 0; s < TOPK; ++s) {
        float bv = FLT_MAX; int bp = 0x7fffffff; int bk = 0;
        #pragma unroll
        for (int k = 0; k < NCAND; ++k) {
            bool ok = !((used >> k) & 1ull);
            bool better = ok && ((cv[k] < bv) || (cv[k] == bv && cp[k] < bp));
            if (better) { bv = cv[k]; bp = cp[k]; bk = k; }
        }
        used |= (1ull << bk);
        float val = expf(-0.1f * sqrtf(fmaxf(bv, 1e-6f)));
        orow[ord[bp]] = val;
    }
}

// ---------------------------------------------------------------------------
extern "C" void kernel_launch(void* const* d_in, const int* in_sizes, int n_in,
                              void* d_out, int out_size, void* d_ws, size_t ws_size,
                              hipStream_t stream) {
    const float* points = (const float*)d_in[0];
    const float* rot    = (const float*)d_in[1];
    float* out = (float*)d_out;

    char* ws = (char*)d_ws;
    int*   bin_idx = (int*)ws;   ws += NBATCH * NPTS * sizeof(int);
    float* na      = (float*)ws; ws += NBATCH * NPTS * sizeof(float);
    int*   order   = (int*)ws;   ws += NBATCH * NPTS * sizeof(int);
    float* wv      = (float*)ws; ws += (size_t)NBATCH * NPTS * NCAND * sizeof(float);
    int*   wd      = (int*)ws;   // total ws use ~3.4 MB

    // Zero via the runtime's fill kernel — proven 6.9 TB/s on this chip.
    hipMemsetAsync(d_out, 0, (size_t)out_size * sizeof(float), stream);

    bin_norm_k<<<(NBATCH * NPTS) / 4, 256, 0, stream>>>(points, rot, bin_idx, na);
    sort_k<<<NBATCH, 256, 0, stream>>>(bin_idx, order);
    pair_topk_k<<<NBATCH * NB * NCB, 256, 0, stream>>>(points, na, order, wv, wd);
    merge_inject_k<<<(NBATCH * NPTS + 255) / 256, 256, 0, stream>>>(wv, wd, order, out);
}